// Round 10
// baseline (384.099 us; speedup 1.0000x reference)
//
#include <hip/hip_runtime.h>
#include <math.h>

#define HDIM 512
#define BATCH 128

typedef _Float16 f16x8 __attribute__((ext_vector_type(8)));
typedef float f32x4 __attribute__((ext_vector_type(4)));

__device__ __forceinline__ float fast_tanh(float x) {
  float e = __expf(2.0f * x);
  return 1.0f - 2.0f / (e + 1.0f);
}

__device__ __forceinline__ void gload_lds16(const void* g, void* l) {
  __builtin_amdgcn_global_load_lds(
      (const __attribute__((address_space(1))) unsigned int*)g,
      (__attribute__((address_space(3))) unsigned int*)l, 16, 0, 0);
}

// ===========================================================================
// A2 fragment layout (NO LDS for A in the GEMM):
//   element A[row][k]  ->  f16 index
//     frag = (k>>6)*2 + ((k>>5)&1)            // kt*2+ks
//     rb   = row>>4
//     lane = (row&15) + (((k>>3)&3)<<4)
//     j    = k&7
//     off  = (frag*(M/16) + rb)*512 + lane*8 + j
// Each 1KB fragment is exactly one wave's mfma_f32_16x16x32_f16 A-operand:
// one coalesced global_load_dwordx4 per wave (lane l -> off base + l*16).
// ===========================================================================

// A [Mrows][512] fp32 -> A2frag rows [m_off..m_off+Mrows). grid (4096, 4).
__global__ __launch_bounds__(256) void cvt_all_kernel(
    const float* __restrict__ tok, const float* __restrict__ node,
    const float* __restrict__ da, const float* __restrict__ dn,
    _Float16* __restrict__ A2tok, _Float16* __restrict__ A2node,
    _Float16* __restrict__ A2desc) {
  const int seg = blockIdx.y;
  const float* A;
  _Float16* A2;
  int M16, m_off, Mrows;
  bool do_tanh = false;
  if (seg == 0)      { A = tok;  A2 = A2tok;  M16 = 4096; m_off = 0;     Mrows = 65536; }
  else if (seg == 1) { A = node; A2 = A2node; M16 = 4096; m_off = 0;     Mrows = 65536; do_tanh = true; }
  else if (seg == 2) { A = da;   A2 = A2desc; M16 = 2048; m_off = 0;     Mrows = 16384; }
  else               { A = dn;   A2 = A2desc; M16 = 2048; m_off = 16384; Mrows = 16384; }
  const int total = Mrows * 64;  // 16B chunks (8 f16 each)
  for (int i = blockIdx.x * 256 + threadIdx.x; i < total; i += gridDim.x * 256) {
    const int m = i >> 6, c = i & 63;  // chunk c covers k = c*8 .. c*8+7
    const float* src = A + (size_t)m * HDIM + c * 8;
    const float4 x = ((const float4*)src)[0];
    const float4 y = ((const float4*)src)[1];
    f16x8 h;
    if (do_tanh) {
      h[0] = (_Float16)fast_tanh(x.x); h[1] = (_Float16)fast_tanh(x.y);
      h[2] = (_Float16)fast_tanh(x.z); h[3] = (_Float16)fast_tanh(x.w);
      h[4] = (_Float16)fast_tanh(y.x); h[5] = (_Float16)fast_tanh(y.y);
      h[6] = (_Float16)fast_tanh(y.z); h[7] = (_Float16)fast_tanh(y.w);
    } else {
      h[0] = (_Float16)x.x; h[1] = (_Float16)x.y;
      h[2] = (_Float16)x.z; h[3] = (_Float16)x.w;
      h[4] = (_Float16)y.x; h[5] = (_Float16)y.y;
      h[6] = (_Float16)y.z; h[7] = (_Float16)y.w;
    }
    const int dr = m_off + m;
    const int frag = (c >> 3) * 2 + ((c >> 2) & 1);
    const int lane = (dr & 15) + ((c & 3) << 4);
    _Float16* dst = A2 + ((size_t)frag * M16 + (dr >> 4)) * 512 + lane * 8;
    *(f16x8*)dst = h;
  }
}

// W [512 k][512 n] fp32 -> W2 [8 kt][512 n][64 k] f16, rows XOR-swizzled
// (byte ^= (n&7)<<4) — unchanged champion layout. grid (128, 3).
__global__ __launch_bounds__(256) void cvt_w3_kernel(
    const float* __restrict__ Wt, const float* __restrict__ Wa,
    const float* __restrict__ Wd, _Float16* __restrict__ W2t,
    _Float16* __restrict__ W2a, _Float16* __restrict__ W2d) {
  const int i = blockIdx.x * 256 + threadIdx.x;  // 512*64
  if (i >= 512 * 64) return;
  const float* W = (blockIdx.y == 0) ? Wt : (blockIdx.y == 1) ? Wa : Wd;
  _Float16* W2 = (blockIdx.y == 0) ? W2t : (blockIdx.y == 1) ? W2a : W2d;
  const int n = i & 511, g = i >> 9;
  const int kt = g >> 3, cc = g & 7;
  f16x8 h;
#pragma unroll
  for (int j = 0; j < 8; ++j)
    h[j] = (_Float16)W[(size_t)(kt * 64 + cc * 8 + j) * HDIM + n];
  char* dst = (char*)W2 + ((size_t)kt * 512 + n) * 128 + ((cc * 16) ^ ((n & 7) << 4));
  *(f16x8*)dst = h;
}

// ---------------------------------------------------------------------------
// Merged fused logit GEMM, A-fragments direct global->VGPR (no LDS for A):
//   logits[m] += sum_n v[n] * tanh( (A@W)[m,n] + bias[n] )   (+c skipped)
// BM=128, BN=256, BK=64; 256 thr = 4 waves (2M x 2N), wave tile 64x128,
// acc 4x8. LDS: Bs only, 2 x 32 KB dbuf -> 2 blocks/CU.
// Per K-tile t: LOAD_A(t+1) [8 reg gloads] + STAGE_B(t+1) [8 gload_lds];
//   vmcnt(16) [drains tile t's A+B, keeps t+1's 16 in flight]; barrier;
//   COMPUTE (16 bF ds_reads + 64 MFMA, A from regs); barrier.
// Segments: 1024 tok + 1024 node + 512 desc = 2560 blocks (XCD-bijective).
// ---------------------------------------------------------------------------
__global__ __launch_bounds__(256, 2) void gemm_logits_frag_kernel(
    const _Float16* __restrict__ A2tok, const _Float16* __restrict__ A2node,
    const _Float16* __restrict__ A2desc,
    const _Float16* __restrict__ W2t, const _Float16* __restrict__ W2a,
    const _Float16* __restrict__ W2d,
    const float* __restrict__ bt, const float* __restrict__ vt,
    const float* __restrict__ ba, const float* __restrict__ va,
    const float* __restrict__ bd, const float* __restrict__ vd,
    float* __restrict__ logits_tok, float* __restrict__ logits_node,
    float* __restrict__ logits_desc) {
  __shared__ __align__(16) _Float16 Bs[2][256 * 64];  // 2 x 32 KB

  const int tid = threadIdx.x;
  const int raw = (int)blockIdx.x;               // 2560 blocks
  const int swz = (raw & 7) * 320 + (raw >> 3);  // XCD-bijective (2560%8==0)

  int id, local;
  if (swz < 1024)      { id = 0; local = swz; }
  else if (swz < 2048) { id = 1; local = swz - 1024; }
  else                 { id = 2; local = swz - 2048; }
  const int mb = local >> 1, nb = local & 1;   // consecutive swz share A-panel
  const _Float16* A2 = (id == 0) ? A2tok : (id == 1) ? A2node : A2desc;
  const _Float16* W2 = (id == 0) ? W2t : (id == 1) ? W2a : W2d;
  const float* bias = (id == 0) ? bt : (id == 1) ? ba : bd;
  const float* vvec = (id == 0) ? vt : (id == 1) ? va : vd;
  float* logits = (id == 0) ? logits_tok : (id == 1) ? logits_node : logits_desc;
  const int M16 = (id == 2) ? 2048 : 4096;
  const size_t m0 = (size_t)mb * 128;
  const int n0 = nb * 256;

  const int lane = tid & 63, wid = tid >> 6;   // 4 waves
  const int tx = lane & 15, qd = lane >> 4;
  const int wm = wid >> 1;   // 0..1 -> rows wm*64..+63
  const int wn = wid & 1;    // 0..1 -> cols wn*128..+127

  // A-fragment base: fragment (kt,ks,i): aBase + ((kt*2+ks)*M16 + i)*512
  const _Float16* aBase = A2 + ((size_t)(m0 >> 4) + wm * 4) * 512 + lane * 8;
  const char* gB = (const char*)W2 + (size_t)n0 * 128;

  f32x4 acc[4][8];
#pragma unroll
  for (int i = 0; i < 4; ++i)
#pragma unroll
    for (int j = 0; j < 8; ++j) acc[i][j] = (f32x4){0.f, 0.f, 0.f, 0.f};

  f16x8 aR[2][2][4];  // [parity][ks][i] — all indices compile-time (rule #20)

  auto LOAD_A = [&](int par, int kt) {
#pragma unroll
    for (int ks = 0; ks < 2; ++ks)
#pragma unroll
      for (int i = 0; i < 4; ++i)
        aR[par][ks][i] =
            *(const f16x8*)(aBase + ((size_t)(kt * 2 + ks) * M16 + i) * 512);
  };
  auto STAGE_B = [&](int buf, int kt) {
    const char* b = gB + (size_t)kt * 65536;
#pragma unroll
    for (int p = 0; p < 8; ++p)
      gload_lds16(b + tid * 16 + p * 4096, (char*)Bs[buf] + tid * 16 + p * 4096);
  };
  auto COMPUTE = [&](int par, int buf) {
#pragma unroll
    for (int ks = 0; ks < 2; ++ks) {
#pragma unroll
      for (int half = 0; half < 2; ++half) {
        f16x8 bF[4];
#pragma unroll
        for (int f = 0; f < 4; ++f) {
          const int n = wn * 128 + (half * 4 + f) * 16 + tx;
          int by = n * 128 + ((ks * 64 + qd * 16) ^ ((n & 7) << 4));
          bF[f] = *(const f16x8*)((const char*)Bs[buf] + by);
        }
        __builtin_amdgcn_s_setprio(1);
#pragma unroll
        for (int i = 0; i < 4; ++i)
#pragma unroll
          for (int f = 0; f < 4; ++f)
            acc[i][half * 4 + f] = __builtin_amdgcn_mfma_f32_16x16x32_f16(
                aR[par][ks][i], bF[f], acc[i][half * 4 + f], 0, 0, 0);
        __builtin_amdgcn_s_setprio(0);
      }
    }
  };

  LOAD_A(0, 0);
  STAGE_B(0, 0);
#pragma unroll
  for (int t = 0; t < 8; ++t) {
    const int cur = t & 1;
    if (t < 7) {
      LOAD_A(cur ^ 1, t + 1);   // 8 reg gloads (older of the new 16)
      STAGE_B(cur ^ 1, t + 1);  // 8 gload_lds
      // keep newest 16 (tile t+1) in flight; drain tile t's A regs + B DMA
      asm volatile("s_waitcnt vmcnt(16)" ::: "memory");
    } else {
      asm volatile("s_waitcnt vmcnt(0)" ::: "memory");
    }
    __builtin_amdgcn_s_barrier();   // everyone's B(t) visible in Bs[cur]
    asm volatile("" ::: "memory");
    COMPUTE(cur, cur);
    asm volatile("" ::: "memory");
    __builtin_amdgcn_s_barrier();   // Bs[cur] reads done before t+2 overwrite
    asm volatile("" ::: "memory");
  }

  // epilogue: t = tanh(acc + bias[n]) * v[n], reduce over this block's 256 n's
  float vv[8], bb[8];
#pragma unroll
  for (int j = 0; j < 8; ++j) {
    const int n = n0 + wn * 128 + j * 16 + tx;
    vv[j] = vvec[n];
    bb[j] = bias[n];
  }
#pragma unroll
  for (int i = 0; i < 4; ++i) {
#pragma unroll
    for (int r = 0; r < 4; ++r) {
      float s = 0.0f;
#pragma unroll
      for (int j = 0; j < 8; ++j)
        s = fmaf(vv[j], fast_tanh(acc[i][j][r] + bb[j]), s);
      s += __shfl_xor(s, 1);
      s += __shfl_xor(s, 2);
      s += __shfl_xor(s, 4);
      s += __shfl_xor(s, 8);
      if (tx == 0)
        atomicAdd(&logits[m0 + wm * 64 + i * 16 + qd * 4 + r], s);
    }
  }
}

// ---------------------------------------------------------------------------
// small/streaming kernels
// ---------------------------------------------------------------------------

__global__ void zero_kernel(float* __restrict__ p, int n) {
  const int i = blockIdx.x * 256 + threadIdx.x;
  if (i < n) p[i] = 0.0f;
}

__global__ void seg_bounds_kernel(const int* __restrict__ seg, int N,
                                  int* __restrict__ seg_start) {
  const int b = threadIdx.x;
  if (b > BATCH) return;
  int lo = 0, hi = N;
  while (lo < hi) {
    const int mid = (lo + hi) >> 1;
    if (seg[mid] < b) lo = mid + 1; else hi = mid;
  }
  seg_start[b] = lo;
}

__global__ __launch_bounds__(256) void softmax_all_kernel(
    float* __restrict__ ltok, float* __restrict__ ldesc,
    float* __restrict__ lnode, const int* __restrict__ tlen,
    const int* __restrict__ dalen, const int* __restrict__ dnlen,
    const int* __restrict__ seg_start) {
  __shared__ float smax[4], ssum[4];
  const int b = blockIdx.x, mode = blockIdx.y, tid = threadIdx.x;
  float* l;
  int s0, s1, fill_end;
  if (mode == 0)      { l = ltok + (size_t)b * 512;          s0 = 0; s1 = tlen[b];  fill_end = 512; }
  else if (mode == 1) { l = ldesc + (size_t)b * 128;         s0 = 0; s1 = dalen[b]; fill_end = 128; }
  else if (mode == 2) { l = ldesc + 16384 + (size_t)b * 128; s0 = 0; s1 = dnlen[b]; fill_end = 128; }
  else                { l = lnode; s0 = seg_start[b]; s1 = seg_start[b + 1]; fill_end = -1; }

  float mymax = -1e30f;
  for (int s = s0 + tid; s < s1; s += 256) mymax = fmaxf(mymax, l[s]);
#pragma unroll
  for (int off = 32; off; off >>= 1) mymax = fmaxf(mymax, __shfl_xor(mymax, off));
  if ((tid & 63) == 0) smax[tid >> 6] = mymax;
  __syncthreads();
  const float bmax = fmaxf(fmaxf(smax[0], smax[1]), fmaxf(smax[2], smax[3]));
  float mysum = 0.0f;
  for (int s = s0 + tid; s < s1; s += 256) mysum += __expf(l[s] - bmax);
#pragma unroll
  for (int off = 32; off; off >>= 1) mysum += __shfl_xor(mysum, off);
  if ((tid & 63) == 0) ssum[tid >> 6] = mysum;
  __syncthreads();
  const float inv = 1.0f / (ssum[0] + ssum[1] + ssum[2] + ssum[3]);
  for (int s = s0 + tid; s < s1; s += 256) l[s] = __expf(l[s] - bmax) * inv;
  if (fill_end > 0)
    for (int s = s1 + tid; s < fill_end; s += 256) l[s] = 0.0f;
}

// read A2frag element pair (row, h even): returns 2 f16 packed in u32
__device__ __forceinline__ unsigned frag_read2(
    const _Float16* __restrict__ A2, int M16, int row, int h) {
  const int frag = (h >> 6) * 2 + ((h >> 5) & 1);
  const int lane = (row & 15) + (((h >> 3) & 3) << 4);
  const size_t off = ((size_t)frag * M16 + (row >> 4)) * 512 + lane * 8 + (h & 7);
  return *(const unsigned*)((const char*)A2 + off * 2);
}

// grid (128, 12): c<8 token chunks, c in {8,9} desc-anchor, {10,11} desc-neg
__global__ __launch_bounds__(256) void pool_masked_all_kernel(
    const _Float16* __restrict__ A2tok, const _Float16* __restrict__ A2desc,
    const float* __restrict__ ltok, const float* __restrict__ ldesc,
    float* __restrict__ tok_pool, float* __restrict__ da_pool,
    float* __restrict__ dn_pool) {
  const int b = blockIdx.x, c = blockIdx.y, tid = threadIdx.x;
  const _Float16* A2;
  const float* w;
  float* out;
  int M16, rbase, s0;
  if (c < 8)       { A2 = A2tok;  M16 = 4096; rbase = b * 512;         w = ltok;  out = tok_pool; s0 = c * 64; }
  else if (c < 10) { A2 = A2desc; M16 = 2048; rbase = b * 128;         w = ldesc; out = da_pool;  s0 = (c - 8) * 64; }
  else             { A2 = A2desc; M16 = 2048; rbase = 16384 + b * 128; w = ldesc; out = dn_pool;  s0 = (c - 10) * 64; }
  const int h = tid * 2;
  float ax = 0.0f, ay = 0.0f;
  for (int s = s0; s < s0 + 64; ++s) {
    const int row = rbase + s;
    const float wsc = w[row];
    if (wsc != 0.0f) {
      const unsigned u = frag_read2(A2, M16, row, h);
      const _Float16* hp = (const _Float16*)&u;
      ax = fmaf(wsc, (float)hp[0], ax);
      ay = fmaf(wsc, (float)hp[1], ay);
    }
  }
  atomicAdd(&out[b * HDIM + h], ax);
  atomicAdd(&out[b * HDIM + h + 1], ay);
}

// ast_pool[b,h] += sum_{n in seg b} w[n] * A2node[n,h] (tanh pre-applied)
__global__ __launch_bounds__(256) void pool_tiled_seg_kernel(
    const _Float16* __restrict__ A2, const float* __restrict__ w,
    const int* __restrict__ seg_start, float* __restrict__ pool) {
  const int b = blockIdx.x, c = blockIdx.y, tid = threadIdx.x;
  const int h = tid * 2;
  const int s0 = seg_start[b], s1 = seg_start[b + 1];
  const int nseg = s1 - s0;
  const int chunk = (nseg + (int)gridDim.y - 1) / (int)gridDim.y;
  const int a0 = s0 + c * chunk;
  const int a1 = min(s1, a0 + chunk);
  float ax = 0.0f, ay = 0.0f;
  for (int s = a0; s < a1; ++s) {
    const float wsc = w[s];
    const unsigned u = frag_read2(A2, 4096, s, h);
    const _Float16* hp = (const _Float16*)&u;
    ax = fmaf(wsc, (float)hp[0], ax);
    ay = fmaf(wsc, (float)hp[1], ay);
  }
  atomicAdd(&pool[b * HDIM + h], ax);
  atomicAdd(&pool[b * HDIM + h + 1], ay);
}

// code-pre GEMM: parts[kb][b][n-chunk] = tanh(cat)[b][k-chunk] @ Wf[k-chunk][n-chunk]
__global__ __launch_bounds__(256) void code_gemm_kernel(
    const float* __restrict__ tok_pool, const float* __restrict__ ast_pool,
    const float* __restrict__ Wf, float* __restrict__ parts) {
  __shared__ float catS[128][65];
  __shared__ float4 wfS[64][32];
  const int nb = blockIdx.x, kb = blockIdx.y, tid = threadIdx.x;
  const int k0 = kb * 64;
  const float* src = (k0 < 512) ? (tok_pool + k0) : (ast_pool + (k0 - 512));
  for (int i = tid; i < 128 * 16; i += 256) {
    const int r = i >> 4, c4 = i & 15;
    const float4 v = *(const float4*)(src + (size_t)r * HDIM + c4 * 4);
    catS[r][c4 * 4 + 0] = fast_tanh(v.x);
    catS[r][c4 * 4 + 1] = fast_tanh(v.y);
    catS[r][c4 * 4 + 2] = fast_tanh(v.z);
    catS[r][c4 * 4 + 3] = fast_tanh(v.w);
  }
  for (int i = tid; i < 64 * 32; i += 256) {
    const int r = i >> 5, c = i & 31;
    wfS[r][c] = *(const float4*)(Wf + (size_t)(k0 + r) * HDIM + nb * 128 + c * 4);
  }
  __syncthreads();
  const int tb = tid >> 4, tn = tid & 15;
  const int b0 = tb * 8, n0l = tn * 8;
  float acc[8][8];
#pragma unroll
  for (int i = 0; i < 8; ++i)
#pragma unroll
    for (int j = 0; j < 8; ++j) acc[i][j] = 0.0f;
  for (int k = 0; k < 64; ++k) {
    float a[8];
#pragma unroll
    for (int i = 0; i < 8; ++i) a[i] = catS[b0 + i][k];
    const float4 w0 = wfS[k][tn * 2], w1 = wfS[k][tn * 2 + 1];
    const float wv[8] = {w0.x, w0.y, w0.z, w0.w, w1.x, w1.y, w1.z, w1.w};
#pragma unroll
    for (int i = 0; i < 8; ++i)
#pragma unroll
      for (int j = 0; j < 8; ++j) acc[i][j] = fmaf(a[i], wv[j], acc[i][j]);
  }
  float* dst = parts + ((size_t)kb * 128) * HDIM + nb * 128;
#pragma unroll
  for (int i = 0; i < 8; ++i) {
    const float4 o0 = {acc[i][0], acc[i][1], acc[i][2], acc[i][3]};
    const float4 o1 = {acc[i][4], acc[i][5], acc[i][6], acc[i][7]};
    *(float4*)(dst + (size_t)(b0 + i) * HDIM + n0l) = o0;
    *(float4*)(dst + (size_t)(b0 + i) * HDIM + n0l + 4) = o1;
  }
}

// per-sample hinge terms; folds code = tanh(sum_kb parts + bf). grid 128.
__global__ __launch_bounds__(256) void sims_kernel(
    const float* __restrict__ parts, const float* __restrict__ bfv,
    const float* __restrict__ da_pool, const float* __restrict__ dn_pool,
    float* __restrict__ terms) {
  __shared__ float sr[4][5];
  const int b = blockIdx.x, tid = threadIdx.x;
  float c2 = 0, a2 = 0, n2 = 0, ca = 0, cn = 0;
  for (int i = tid; i < HDIM; i += 256) {
    float pre = bfv[i];
#pragma unroll
    for (int kb = 0; kb < 16; ++kb)
      pre += parts[((size_t)kb * 128 + b) * HDIM + i];
    const float cf = fast_tanh(pre);
    const float av = fast_tanh(fast_tanh(da_pool[(size_t)b * HDIM + i]));
    const float nv = fast_tanh(fast_tanh(dn_pool[(size_t)b * HDIM + i]));
    c2 = fmaf(cf, cf, c2); a2 = fmaf(av, av, a2); n2 = fmaf(nv, nv, n2);
    ca = fmaf(cf, av, ca); cn = fmaf(cf, nv, cn);
  }
#pragma unroll
  for (int off = 32; off; off >>= 1) {
    c2 += __shfl_xor(c2, off); a2 += __shfl_xor(a2, off); n2 += __shfl_xor(n2, off);
    ca += __shfl_xor(ca, off); cn += __shfl_xor(cn, off);
  }
  const int wv = tid >> 6;
  if ((tid & 63) == 0) {
    sr[wv][0] = c2; sr[wv][1] = a2; sr[wv][2] = n2; sr[wv][3] = ca; sr[wv][4] = cn;
  }
  __syncthreads();
  if (tid == 0) {
    c2 = sr[0][0] + sr[1][0] + sr[2][0] + sr[3][0];
    a2 = sr[0][1] + sr[1][1] + sr[2][1] + sr[3][1];
    n2 = sr[0][2] + sr[1][2] + sr[2][2] + sr[3][2];
    ca = sr[0][3] + sr[1][3] + sr[2][3] + sr[3][3];
    cn = sr[0][4] + sr[1][4] + sr[2][4] + sr[3][4];
    const float nc = fmaxf(sqrtf(c2), 1e-8f);
    const float na = fmaxf(sqrtf(a2), 1e-8f);
    const float nn = fmaxf(sqrtf(n2), 1e-8f);
    terms[b] = fmaxf(0.05f - ca / (nc * na) + cn / (nc * nn), 1e-6f);
  }
}

__global__ void loss_kernel(const float* __restrict__ terms, float* __restrict__ out) {
  const int tid = threadIdx.x;  // 128
  float v = terms[tid];
#pragma unroll
  for (int off = 32; off; off >>= 1) v += __shfl_xor(v, off);
  __shared__ float sr[2];
  if ((tid & 63) == 0) sr[tid >> 6] = v;
  __syncthreads();
  if (tid == 0) out[0] = (sr[0] + sr[1]) * (1.0f / (float)BATCH);
}

// ===========================================================================

extern "C" void kernel_launch(void* const* d_in, const int* in_sizes, int n_in,
                              void* d_out, int out_size, void* d_ws, size_t ws_size,
                              hipStream_t stream) {
  (void)in_sizes; (void)n_in; (void)out_size; (void)ws_size;
  const float* token_feat = (const float*)d_in[0];
  const int*   token_len  = (const int*)d_in[1];
  const float* node_h     = (const float*)d_in[2];
  const int*   seg_ids    = (const int*)d_in[3];
  const float* da_feat    = (const float*)d_in[4];
  const int*   da_len     = (const int*)d_in[5];
  const float* dn_feat    = (const float*)d_in[6];
  const int*   dn_len     = (const int*)d_in[7];
  const float* Wt = (const float*)d_in[8];
  const float* bt = (const float*)d_in[9];
  const float* vt = (const float*)d_in[10];
  const float* Wa = (const float*)d_in[12];
  const float* ba = (const float*)d_in[13];
  const float* va = (const float*)d_in[14];
  const float* Wd = (const float*)d_in[16];
  const float* bd = (const float*)d_in[17];
  const float* vd = (const float*)d_in[18];
  const float* Wf  = (const float*)d_in[20];
  const float* bfv = (const float*)d_in[21];

  const int MTOK = 65536;
  const int MDESC2 = 32768;
  const int NNODES = 65536;

  float* ws = (float*)d_ws;
  float* logits_tok  = ws;                       // 65536 (atomic)
  float* logits_node = logits_tok + MTOK;        // 65536
  float* logits_desc = logits_node + NNODES;     // 32768 (da ++ dn)
  float* tok_pool    = logits_desc + MDESC2;
  float* ast_pool    = tok_pool + 128 * HDIM;
  float* da_pool     = ast_pool + 128 * HDIM;
  float* dn_pool     = da_pool + 128 * HDIM;
  float* terms       = dn_pool + 128 * HDIM;     // 128
  int*   seg_start   = (int*)(terms + 128);      // 256 slot
  float* parts       = (float*)(seg_start + 256);  // 16*128*512
  _Float16* W2t = (_Float16*)(parts + 16 * 128 * HDIM);
  _Float16* W2a = W2t + HDIM * HDIM;
  _Float16* W2d = W2a + HDIM * HDIM;
  _Float16* A2tok  = W2d + HDIM * HDIM;               // 65536*512 f16 (frag)
  _Float16* A2node = A2tok + (size_t)MTOK * 512;
  _Float16* A2desc = A2node + (size_t)NNODES * 512;   // 32768*512 f16 (frag)

  // zero atomically-accumulated buffers: logits + pools
  const int ZTOT = MTOK + NNODES + MDESC2 + 4 * 128 * HDIM;
  zero_kernel<<<dim3((ZTOT + 255) / 256), 256, 0, stream>>>(ws, ZTOT);
  seg_bounds_kernel<<<1, 256, 0, stream>>>(seg_ids, NNODES, seg_start);

  // convert weights + activations (A -> MFMA-fragment layout)
  cvt_w3_kernel<<<dim3(128, 3), 256, 0, stream>>>(Wt, Wa, Wd, W2t, W2a, W2d);
  cvt_all_kernel<<<dim3(4096, 4), 256, 0, stream>>>(
      token_feat, node_h, da_feat, dn_feat, A2tok, A2node, A2desc);

  // ONE merged GEMM: 1024 tok + 1024 node + 512 desc = 2560 blocks
  gemm_logits_frag_kernel<<<2560, 256, 0, stream>>>(
      A2tok, A2node, A2desc, W2t, W2a, W2d,
      bt, vt, ba, va, bd, vd, logits_tok, logits_node, logits_desc);

  softmax_all_kernel<<<dim3(BATCH, 4), 256, 0, stream>>>(
      logits_tok, logits_desc, logits_node, token_len, da_len, dn_len, seg_start);

  pool_masked_all_kernel<<<dim3(BATCH, 12), 256, 0, stream>>>(
      A2tok, A2desc, logits_tok, logits_desc, tok_pool, da_pool, dn_pool);
  pool_tiled_seg_kernel<<<dim3(BATCH, 4), 256, 0, stream>>>(
      A2node, logits_node, seg_start, ast_pool);

  code_gemm_kernel<<<dim3(4, 16), 256, 0, stream>>>(tok_pool, ast_pool, Wf, parts);
  sims_kernel<<<BATCH, 256, 0, stream>>>(parts, bfv, da_pool, dn_pool, terms);
  loss_kernel<<<1, 128, 0, stream>>>(terms, (float*)d_out);
}

// Round 12
// 309.551 us; speedup vs baseline: 1.2408x; 1.2408x over previous
//
#include <hip/hip_runtime.h>
#include <math.h>

#define HDIM 512
#define BATCH 128

typedef _Float16 f16x8 __attribute__((ext_vector_type(8)));
typedef float f32x4 __attribute__((ext_vector_type(4)));

__device__ __forceinline__ float fast_tanh(float x) {
  float e = __expf(2.0f * x);
  return 1.0f - 2.0f / (e + 1.0f);
}

__device__ __forceinline__ void gload_lds16(const void* g, void* l) {
  __builtin_amdgcn_global_load_lds(
      (const __attribute__((address_space(1))) unsigned int*)g,
      (__attribute__((address_space(3))) unsigned int*)l, 16, 0, 0);
}

// ===========================================================================
// A2 fragment layout (NO LDS for A in the GEMM):
//   element A[row][k]  ->  f16 index
//     frag = (k>>6)*2 + ((k>>5)&1)            // kt*2+ks
//     rb   = row>>4
//     lane = (row&15) + (((k>>3)&3)<<4)
//     j    = k&7
//     off  = (frag*(M/16) + rb)*512 + lane*8 + j
// Each 1KB fragment is exactly one wave's mfma_f32_16x16x32_f16 A-operand.
// ===========================================================================

// ---------------------------------------------------------------------------
// Wave-per-fragment converter: each wave reads a 16-row x 32-k fp32 sub-tile
// (lane l -> SOURCE-LOCAL row (rb-rb_base)*16+(l&15), k-chunk l>>4; 4 lanes
// per row = 128B contiguous reads) and writes one 1KB fragment contiguously
// (lane l -> +l*16B) at DEST-GLOBAL rb. R11 bug: used global rb for the
// source read -> 33MB OOB on dn_feat -> abort. Now decoupled.
// grid (4096, 4): y = segment.
// ---------------------------------------------------------------------------
__global__ __launch_bounds__(256) void cvt_frag_kernel(
    const float* __restrict__ tok, const float* __restrict__ node,
    const float* __restrict__ da, const float* __restrict__ dn,
    _Float16* __restrict__ A2tok, _Float16* __restrict__ A2node,
    _Float16* __restrict__ A2desc) {
  const int seg = blockIdx.y;
  const float* A;
  _Float16* A2;
  int M16, rb_base, rb_bits;  // fragments per band = 1<<rb_bits
  bool do_tanh = false;
  if (seg == 0)      { A = tok;  A2 = A2tok;  M16 = 4096; rb_base = 0;    rb_bits = 12; }
  else if (seg == 1) { A = node; A2 = A2node; M16 = 4096; rb_base = 0;    rb_bits = 12; do_tanh = true; }
  else if (seg == 2) { A = da;   A2 = A2desc; M16 = 2048; rb_base = 0;    rb_bits = 10; }
  else               { A = dn;   A2 = A2desc; M16 = 2048; rb_base = 1024; rb_bits = 10; }
  const int lane = threadIdx.x & 63, wid = threadIdx.x >> 6;
  const int total = 16 << rb_bits;           // fragments in this segment
  const int rl = lane & 15, kc = lane >> 4;  // row-in-block, k-chunk
  for (int fl = blockIdx.x * 4 + wid; fl < total; fl += gridDim.x * 4) {
    const int frag = fl >> rb_bits;
    const int rb_local = fl & ((1 << rb_bits) - 1);
    const int rb = rb_base + rb_local;           // destination row-block
    const int kt = frag >> 1, ks = frag & 1;
    const int row_src = rb_local * 16 + rl;      // SOURCE row (local to A)
    const int k = kt * 64 + ks * 32 + kc * 8;
    const float4* src = (const float4*)(A + (size_t)row_src * HDIM + k);
    const float4 x = src[0];
    const float4 y = src[1];
    f16x8 h;
    if (do_tanh) {
      h[0] = (_Float16)fast_tanh(x.x); h[1] = (_Float16)fast_tanh(x.y);
      h[2] = (_Float16)fast_tanh(x.z); h[3] = (_Float16)fast_tanh(x.w);
      h[4] = (_Float16)fast_tanh(y.x); h[5] = (_Float16)fast_tanh(y.y);
      h[6] = (_Float16)fast_tanh(y.z); h[7] = (_Float16)fast_tanh(y.w);
    } else {
      h[0] = (_Float16)x.x; h[1] = (_Float16)x.y;
      h[2] = (_Float16)x.z; h[3] = (_Float16)x.w;
      h[4] = (_Float16)y.x; h[5] = (_Float16)y.y;
      h[6] = (_Float16)y.z; h[7] = (_Float16)y.w;
    }
    *(f16x8*)(A2 + ((size_t)frag * M16 + rb) * 512 + lane * 8) = h;
  }
}

// W [512 k][512 n] fp32 -> W2 [8 kt][512 n][64 k] f16, rows XOR-swizzled
// (byte ^= (n&7)<<4). grid (128, 3).
__global__ __launch_bounds__(256) void cvt_w3_kernel(
    const float* __restrict__ Wt, const float* __restrict__ Wa,
    const float* __restrict__ Wd, _Float16* __restrict__ W2t,
    _Float16* __restrict__ W2a, _Float16* __restrict__ W2d) {
  const int i = blockIdx.x * 256 + threadIdx.x;  // 512*64
  if (i >= 512 * 64) return;
  const float* W = (blockIdx.y == 0) ? Wt : (blockIdx.y == 1) ? Wa : Wd;
  _Float16* W2 = (blockIdx.y == 0) ? W2t : (blockIdx.y == 1) ? W2a : W2d;
  const int n = i & 511, g = i >> 9;
  const int kt = g >> 3, cc = g & 7;
  f16x8 h;
#pragma unroll
  for (int j = 0; j < 8; ++j)
    h[j] = (_Float16)W[(size_t)(kt * 64 + cc * 8 + j) * HDIM + n];
  char* dst = (char*)W2 + ((size_t)kt * 512 + n) * 128 + ((cc * 16) ^ ((n & 7) << 4));
  *(f16x8*)dst = h;
}

// ---------------------------------------------------------------------------
// Merged fused logit GEMM, A-fragments direct global->VGPR (no LDS for A):
//   logits[m] += sum_n v[n] * tanh( (A@W)[m,n] + bias[n] )   (+c skipped)
// BM=128, BN=256, BK=64; 256 thr = 4 waves (2M x 2N), wave tile 64x128,
// acc 4x8. LDS: Bs only, 2 x 32 KB dbuf -> 2 blocks/CU.  (unchanged from R10)
// ---------------------------------------------------------------------------
__global__ __launch_bounds__(256, 2) void gemm_logits_frag_kernel(
    const _Float16* __restrict__ A2tok, const _Float16* __restrict__ A2node,
    const _Float16* __restrict__ A2desc,
    const _Float16* __restrict__ W2t, const _Float16* __restrict__ W2a,
    const _Float16* __restrict__ W2d,
    const float* __restrict__ bt, const float* __restrict__ vt,
    const float* __restrict__ ba, const float* __restrict__ va,
    const float* __restrict__ bd, const float* __restrict__ vd,
    float* __restrict__ logits_tok, float* __restrict__ logits_node,
    float* __restrict__ logits_desc) {
  __shared__ __align__(16) _Float16 Bs[2][256 * 64];  // 2 x 32 KB

  const int tid = threadIdx.x;
  const int raw = (int)blockIdx.x;               // 2560 blocks
  const int swz = (raw & 7) * 320 + (raw >> 3);  // XCD-bijective (2560%8==0)

  int id, local;
  if (swz < 1024)      { id = 0; local = swz; }
  else if (swz < 2048) { id = 1; local = swz - 1024; }
  else                 { id = 2; local = swz - 2048; }
  const int mb = local >> 1, nb = local & 1;   // consecutive swz share A-panel
  const _Float16* A2 = (id == 0) ? A2tok : (id == 1) ? A2node : A2desc;
  const _Float16* W2 = (id == 0) ? W2t : (id == 1) ? W2a : W2d;
  const float* bias = (id == 0) ? bt : (id == 1) ? ba : bd;
  const float* vvec = (id == 0) ? vt : (id == 1) ? va : vd;
  float* logits = (id == 0) ? logits_tok : (id == 1) ? logits_node : logits_desc;
  const int M16 = (id == 2) ? 2048 : 4096;
  const size_t m0 = (size_t)mb * 128;
  const int n0 = nb * 256;

  const int lane = tid & 63, wid = tid >> 6;   // 4 waves
  const int tx = lane & 15, qd = lane >> 4;
  const int wm = wid >> 1;   // 0..1 -> rows wm*64..+63
  const int wn = wid & 1;    // 0..1 -> cols wn*128..+127

  const _Float16* aBase = A2 + ((size_t)(m0 >> 4) + wm * 4) * 512 + lane * 8;
  const char* gB = (const char*)W2 + (size_t)n0 * 128;

  f32x4 acc[4][8];
#pragma unroll
  for (int i = 0; i < 4; ++i)
#pragma unroll
    for (int j = 0; j < 8; ++j) acc[i][j] = (f32x4){0.f, 0.f, 0.f, 0.f};

  f16x8 aR[2][2][4];  // [parity][ks][i] — compile-time indices (rule #20)

  auto LOAD_A = [&](int par, int kt) {
#pragma unroll
    for (int ks = 0; ks < 2; ++ks)
#pragma unroll
      for (int i = 0; i < 4; ++i)
        aR[par][ks][i] =
            *(const f16x8*)(aBase + ((size_t)(kt * 2 + ks) * M16 + i) * 512);
  };
  auto STAGE_B = [&](int buf, int kt) {
    const char* b = gB + (size_t)kt * 65536;
#pragma unroll
    for (int p = 0; p < 8; ++p)
      gload_lds16(b + tid * 16 + p * 4096, (char*)Bs[buf] + tid * 16 + p * 4096);
  };
  auto COMPUTE = [&](int par, int buf) {
#pragma unroll
    for (int ks = 0; ks < 2; ++ks) {
#pragma unroll
      for (int half = 0; half < 2; ++half) {
        f16x8 bF[4];
#pragma unroll
        for (int f = 0; f < 4; ++f) {
          const int n = wn * 128 + (half * 4 + f) * 16 + tx;
          int by = n * 128 + ((ks * 64 + qd * 16) ^ ((n & 7) << 4));
          bF[f] = *(const f16x8*)((const char*)Bs[buf] + by);
        }
        __builtin_amdgcn_s_setprio(1);
#pragma unroll
        for (int i = 0; i < 4; ++i)
#pragma unroll
          for (int f = 0; f < 4; ++f)
            acc[i][half * 4 + f] = __builtin_amdgcn_mfma_f32_16x16x32_f16(
                aR[par][ks][i], bF[f], acc[i][half * 4 + f], 0, 0, 0);
        __builtin_amdgcn_s_setprio(0);
      }
    }
  };

  LOAD_A(0, 0);
  STAGE_B(0, 0);
#pragma unroll
  for (int t = 0; t < 8; ++t) {
    const int cur = t & 1;
    if (t < 7) {
      LOAD_A(cur ^ 1, t + 1);   // 8 reg gloads (older of the new 16)
      STAGE_B(cur ^ 1, t + 1);  // 8 gload_lds
      asm volatile("s_waitcnt vmcnt(16)" ::: "memory");  // drain tile t only
    } else {
      asm volatile("s_waitcnt vmcnt(0)" ::: "memory");
    }
    __builtin_amdgcn_s_barrier();   // everyone's B(t) visible in Bs[cur]
    asm volatile("" ::: "memory");
    COMPUTE(cur, cur);
    asm volatile("" ::: "memory");
    __builtin_amdgcn_s_barrier();   // Bs[cur] reads done before t+2 overwrite
    asm volatile("" ::: "memory");
  }

  // epilogue: t = tanh(acc + bias[n]) * v[n], reduce over this block's 256 n's
  float vv[8], bb[8];
#pragma unroll
  for (int j = 0; j < 8; ++j) {
    const int n = n0 + wn * 128 + j * 16 + tx;
    vv[j] = vvec[n];
    bb[j] = bias[n];
  }
#pragma unroll
  for (int i = 0; i < 4; ++i) {
#pragma unroll
    for (int r = 0; r < 4; ++r) {
      float s = 0.0f;
#pragma unroll
      for (int j = 0; j < 8; ++j)
        s = fmaf(vv[j], fast_tanh(acc[i][j][r] + bb[j]), s);
      s += __shfl_xor(s, 1);
      s += __shfl_xor(s, 2);
      s += __shfl_xor(s, 4);
      s += __shfl_xor(s, 8);
      if (tx == 0)
        atomicAdd(&logits[m0 + wm * 64 + i * 16 + qd * 4 + r], s);
    }
  }
}

// ---------------------------------------------------------------------------
// small/streaming kernels (unchanged)
// ---------------------------------------------------------------------------

__global__ void zero_kernel(float* __restrict__ p, int n) {
  const int i = blockIdx.x * 256 + threadIdx.x;
  if (i < n) p[i] = 0.0f;
}

__global__ void seg_bounds_kernel(const int* __restrict__ seg, int N,
                                  int* __restrict__ seg_start) {
  const int b = threadIdx.x;
  if (b > BATCH) return;
  int lo = 0, hi = N;
  while (lo < hi) {
    const int mid = (lo + hi) >> 1;
    if (seg[mid] < b) lo = mid + 1; else hi = mid;
  }
  seg_start[b] = lo;
}

__global__ __launch_bounds__(256) void softmax_all_kernel(
    float* __restrict__ ltok, float* __restrict__ ldesc,
    float* __restrict__ lnode, const int* __restrict__ tlen,
    const int* __restrict__ dalen, const int* __restrict__ dnlen,
    const int* __restrict__ seg_start) {
  __shared__ float smax[4], ssum[4];
  const int b = blockIdx.x, mode = blockIdx.y, tid = threadIdx.x;
  float* l;
  int s0, s1, fill_end;
  if (mode == 0)      { l = ltok + (size_t)b * 512;          s0 = 0; s1 = tlen[b];  fill_end = 512; }
  else if (mode == 1) { l = ldesc + (size_t)b * 128;         s0 = 0; s1 = dalen[b]; fill_end = 128; }
  else if (mode == 2) { l = ldesc + 16384 + (size_t)b * 128; s0 = 0; s1 = dnlen[b]; fill_end = 128; }
  else                { l = lnode; s0 = seg_start[b]; s1 = seg_start[b + 1]; fill_end = -1; }

  float mymax = -1e30f;
  for (int s = s0 + tid; s < s1; s += 256) mymax = fmaxf(mymax, l[s]);
#pragma unroll
  for (int off = 32; off; off >>= 1) mymax = fmaxf(mymax, __shfl_xor(mymax, off));
  if ((tid & 63) == 0) smax[tid >> 6] = mymax;
  __syncthreads();
  const float bmax = fmaxf(fmaxf(smax[0], smax[1]), fmaxf(smax[2], smax[3]));
  float mysum = 0.0f;
  for (int s = s0 + tid; s < s1; s += 256) mysum += __expf(l[s] - bmax);
#pragma unroll
  for (int off = 32; off; off >>= 1) mysum += __shfl_xor(mysum, off);
  if ((tid & 63) == 0) ssum[tid >> 6] = mysum;
  __syncthreads();
  const float inv = 1.0f / (ssum[0] + ssum[1] + ssum[2] + ssum[3]);
  for (int s = s0 + tid; s < s1; s += 256) l[s] = __expf(l[s] - bmax) * inv;
  if (fill_end > 0)
    for (int s = s1 + tid; s < fill_end; s += 256) l[s] = 0.0f;
}

// read A2frag element pair (row, h even): returns 2 f16 packed in u32
__device__ __forceinline__ unsigned frag_read2(
    const _Float16* __restrict__ A2, int M16, int row, int h) {
  const int frag = (h >> 6) * 2 + ((h >> 5) & 1);
  const int lane = (row & 15) + (((h >> 3) & 3) << 4);
  const size_t off = ((size_t)frag * M16 + (row >> 4)) * 512 + lane * 8 + (h & 7);
  return *(const unsigned*)((const char*)A2 + off * 2);
}

// grid (128, 12): c<8 token chunks, c in {8,9} desc-anchor, {10,11} desc-neg
__global__ __launch_bounds__(256) void pool_masked_all_kernel(
    const _Float16* __restrict__ A2tok, const _Float16* __restrict__ A2desc,
    const float* __restrict__ ltok, const float* __restrict__ ldesc,
    float* __restrict__ tok_pool, float* __restrict__ da_pool,
    float* __restrict__ dn_pool) {
  const int b = blockIdx.x, c = blockIdx.y, tid = threadIdx.x;
  const _Float16* A2;
  const float* w;
  float* out;
  int M16, rbase, s0;
  if (c < 8)       { A2 = A2tok;  M16 = 4096; rbase = b * 512;         w = ltok;  out = tok_pool; s0 = c * 64; }
  else if (c < 10) { A2 = A2desc; M16 = 2048; rbase = b * 128;         w = ldesc; out = da_pool;  s0 = (c - 8) * 64; }
  else             { A2 = A2desc; M16 = 2048; rbase = 16384 + b * 128; w = ldesc; out = dn_pool;  s0 = (c - 10) * 64; }
  const int h = tid * 2;
  float ax = 0.0f, ay = 0.0f;
  for (int s = s0; s < s0 + 64; ++s) {
    const int row = rbase + s;
    const float wsc = w[row];
    if (wsc != 0.0f) {
      const unsigned u = frag_read2(A2, M16, row, h);
      const _Float16* hp = (const _Float16*)&u;
      ax = fmaf(wsc, (float)hp[0], ax);
      ay = fmaf(wsc, (float)hp[1], ay);
    }
  }
  atomicAdd(&out[b * HDIM + h], ax);
  atomicAdd(&out[b * HDIM + h + 1], ay);
}

// ast_pool[b,h] += sum_{n in seg b} w[n] * A2node[n,h] (tanh pre-applied)
__global__ __launch_bounds__(256) void pool_tiled_seg_kernel(
    const _Float16* __restrict__ A2, const float* __restrict__ w,
    const int* __restrict__ seg_start, float* __restrict__ pool) {
  const int b = blockIdx.x, c = blockIdx.y, tid = threadIdx.x;
  const int h = tid * 2;
  const int s0 = seg_start[b], s1 = seg_start[b + 1];
  const int nseg = s1 - s0;
  const int chunk = (nseg + (int)gridDim.y - 1) / (int)gridDim.y;
  const int a0 = s0 + c * chunk;
  const int a1 = min(s1, a0 + chunk);
  float ax = 0.0f, ay = 0.0f;
  for (int s = a0; s < a1; ++s) {
    const float wsc = w[s];
    const unsigned u = frag_read2(A2, 4096, s, h);
    const _Float16* hp = (const _Float16*)&u;
    ax = fmaf(wsc, (float)hp[0], ax);
    ay = fmaf(wsc, (float)hp[1], ay);
  }
  atomicAdd(&pool[b * HDIM + h], ax);
  atomicAdd(&pool[b * HDIM + h + 1], ay);
}

// code-pre GEMM: parts[kb][b][n-chunk] = tanh(cat)[b][k-chunk] @ Wf[k-chunk][n-chunk]
__global__ __launch_bounds__(256) void code_gemm_kernel(
    const float* __restrict__ tok_pool, const float* __restrict__ ast_pool,
    const float* __restrict__ Wf, float* __restrict__ parts) {
  __shared__ float catS[128][65];
  __shared__ float4 wfS[64][32];
  const int nb = blockIdx.x, kb = blockIdx.y, tid = threadIdx.x;
  const int k0 = kb * 64;
  const float* src = (k0 < 512) ? (tok_pool + k0) : (ast_pool + (k0 - 512));
  for (int i = tid; i < 128 * 16; i += 256) {
    const int r = i >> 4, c4 = i & 15;
    const float4 v = *(const float4*)(src + (size_t)r * HDIM + c4 * 4);
    catS[r][c4 * 4 + 0] = fast_tanh(v.x);
    catS[r][c4 * 4 + 1] = fast_tanh(v.y);
    catS[r][c4 * 4 + 2] = fast_tanh(v.z);
    catS[r][c4 * 4 + 3] = fast_tanh(v.w);
  }
  for (int i = tid; i < 64 * 32; i += 256) {
    const int r = i >> 5, c = i & 31;
    wfS[r][c] = *(const float4*)(Wf + (size_t)(k0 + r) * HDIM + nb * 128 + c * 4);
  }
  __syncthreads();
  const int tb = tid >> 4, tn = tid & 15;
  const int b0 = tb * 8, n0l = tn * 8;
  float acc[8][8];
#pragma unroll
  for (int i = 0; i < 8; ++i)
#pragma unroll
    for (int j = 0; j < 8; ++j) acc[i][j] = 0.0f;
  for (int k = 0; k < 64; ++k) {
    float a[8];
#pragma unroll
    for (int i = 0; i < 8; ++i) a[i] = catS[b0 + i][k];
    const float4 w0 = wfS[k][tn * 2], w1 = wfS[k][tn * 2 + 1];
    const float wv[8] = {w0.x, w0.y, w0.z, w0.w, w1.x, w1.y, w1.z, w1.w};
#pragma unroll
    for (int i = 0; i < 8; ++i)
#pragma unroll
      for (int j = 0; j < 8; ++j) acc[i][j] = fmaf(a[i], wv[j], acc[i][j]);
  }
  float* dst = parts + ((size_t)kb * 128) * HDIM + nb * 128;
#pragma unroll
  for (int i = 0; i < 8; ++i) {
    const float4 o0 = {acc[i][0], acc[i][1], acc[i][2], acc[i][3]};
    const float4 o1 = {acc[i][4], acc[i][5], acc[i][6], acc[i][7]};
    *(float4*)(dst + (size_t)(b0 + i) * HDIM + n0l) = o0;
    *(float4*)(dst + (size_t)(b0 + i) * HDIM + n0l + 4) = o1;
  }
}

// per-sample hinge terms; folds code = tanh(sum_kb parts + bf). grid 128.
__global__ __launch_bounds__(256) void sims_kernel(
    const float* __restrict__ parts, const float* __restrict__ bfv,
    const float* __restrict__ da_pool, const float* __restrict__ dn_pool,
    float* __restrict__ terms) {
  __shared__ float sr[4][5];
  const int b = blockIdx.x, tid = threadIdx.x;
  float c2 = 0, a2 = 0, n2 = 0, ca = 0, cn = 0;
  for (int i = tid; i < HDIM; i += 256) {
    float pre = bfv[i];
#pragma unroll
    for (int kb = 0; kb < 16; ++kb)
      pre += parts[((size_t)kb * 128 + b) * HDIM + i];
    const float cf = fast_tanh(pre);
    const float av = fast_tanh(fast_tanh(da_pool[(size_t)b * HDIM + i]));
    const float nv = fast_tanh(fast_tanh(dn_pool[(size_t)b * HDIM + i]));
    c2 = fmaf(cf, cf, c2); a2 = fmaf(av, av, a2); n2 = fmaf(nv, nv, n2);
    ca = fmaf(cf, av, ca); cn = fmaf(cf, nv, cn);
  }
#pragma unroll
  for (int off = 32; off; off >>= 1) {
    c2 += __shfl_xor(c2, off); a2 += __shfl_xor(a2, off); n2 += __shfl_xor(n2, off);
    ca += __shfl_xor(ca, off); cn += __shfl_xor(cn, off);
  }
  const int wv = tid >> 6;
  if ((tid & 63) == 0) {
    sr[wv][0] = c2; sr[wv][1] = a2; sr[wv][2] = n2; sr[wv][3] = ca; sr[wv][4] = cn;
  }
  __syncthreads();
  if (tid == 0) {
    c2 = sr[0][0] + sr[1][0] + sr[2][0] + sr[3][0];
    a2 = sr[0][1] + sr[1][1] + sr[2][1] + sr[3][1];
    n2 = sr[0][2] + sr[1][2] + sr[2][2] + sr[3][2];
    ca = sr[0][3] + sr[1][3] + sr[2][3] + sr[3][3];
    cn = sr[0][4] + sr[1][4] + sr[2][4] + sr[3][4];
    const float nc = fmaxf(sqrtf(c2), 1e-8f);
    const float na = fmaxf(sqrtf(a2), 1e-8f);
    const float nn = fmaxf(sqrtf(n2), 1e-8f);
    terms[b] = fmaxf(0.05f - ca / (nc * na) + cn / (nc * nn), 1e-6f);
  }
}

__global__ void loss_kernel(const float* __restrict__ terms, float* __restrict__ out) {
  const int tid = threadIdx.x;  // 128
  float v = terms[tid];
#pragma unroll
  for (int off = 32; off; off >>= 1) v += __shfl_xor(v, off);
  __shared__ float sr[2];
  if ((tid & 63) == 0) sr[tid >> 6] = v;
  __syncthreads();
  if (tid == 0) out[0] = (sr[0] + sr[1]) * (1.0f / (float)BATCH);
}

// ===========================================================================

extern "C" void kernel_launch(void* const* d_in, const int* in_sizes, int n_in,
                              void* d_out, int out_size, void* d_ws, size_t ws_size,
                              hipStream_t stream) {
  (void)in_sizes; (void)n_in; (void)out_size; (void)ws_size;
  const float* token_feat = (const float*)d_in[0];
  const int*   token_len  = (const int*)d_in[1];
  const float* node_h     = (const float*)d_in[2];
  const int*   seg_ids    = (const int*)d_in[3];
  const float* da_feat    = (const float*)d_in[4];
  const int*   da_len     = (const int*)d_in[5];
  const float* dn_feat    = (const float*)d_in[6];
  const int*   dn_len     = (const int*)d_in[7];
  const float* Wt = (const float*)d_in[8];
  const float* bt = (const float*)d_in[9];
  const float* vt = (const float*)d_in[10];
  const float* Wa = (const float*)d_in[12];
  const float* ba = (const float*)d_in[13];
  const float* va = (const float*)d_in[14];
  const float* Wd = (const float*)d_in[16];
  const float* bd = (const float*)d_in[17];
  const float* vd = (const float*)d_in[18];
  const float* Wf  = (const float*)d_in[20];
  const float* bfv = (const float*)d_in[21];

  const int MTOK = 65536;
  const int MDESC2 = 32768;
  const int NNODES = 65536;

  float* ws = (float*)d_ws;
  float* logits_tok  = ws;                       // 65536 (atomic)
  float* logits_node = logits_tok + MTOK;        // 65536
  float* logits_desc = logits_node + NNODES;     // 32768 (da ++ dn)
  float* tok_pool    = logits_desc + MDESC2;
  float* ast_pool    = tok_pool + 128 * HDIM;
  float* da_pool     = ast_pool + 128 * HDIM;
  float* dn_pool     = da_pool + 128 * HDIM;
  float* terms       = dn_pool + 128 * HDIM;     // 128
  int*   seg_start   = (int*)(terms + 128);      // 256 slot
  float* parts       = (float*)(seg_start + 256);  // 16*128*512
  _Float16* W2t = (_Float16*)(parts + 16 * 128 * HDIM);
  _Float16* W2a = W2t + HDIM * HDIM;
  _Float16* W2d = W2a + HDIM * HDIM;
  _Float16* A2tok  = W2d + HDIM * HDIM;               // 65536*512 f16 (frag)
  _Float16* A2node = A2tok + (size_t)MTOK * 512;
  _Float16* A2desc = A2node + (size_t)NNODES * 512;   // 32768*512 f16 (frag)

  // zero atomically-accumulated buffers: logits + pools
  const int ZTOT = MTOK + NNODES + MDESC2 + 4 * 128 * HDIM;
  zero_kernel<<<dim3((ZTOT + 255) / 256), 256, 0, stream>>>(ws, ZTOT);
  seg_bounds_kernel<<<1, 256, 0, stream>>>(seg_ids, NNODES, seg_start);

  // convert weights + activations (A -> MFMA-fragment layout, coalesced)
  cvt_w3_kernel<<<dim3(128, 3), 256, 0, stream>>>(Wt, Wa, Wd, W2t, W2a, W2d);
  cvt_frag_kernel<<<dim3(4096, 4), 256, 0, stream>>>(
      token_feat, node_h, da_feat, dn_feat, A2tok, A2node, A2desc);

  // ONE merged GEMM: 1024 tok + 1024 node + 512 desc = 2560 blocks
  gemm_logits_frag_kernel<<<2560, 256, 0, stream>>>(
      A2tok, A2node, A2desc, W2t, W2a, W2d,
      bt, vt, ba, va, bd, vd, logits_tok, logits_node, logits_desc);

  softmax_all_kernel<<<dim3(BATCH, 4), 256, 0, stream>>>(
      logits_tok, logits_desc, logits_node, token_len, da_len, dn_len, seg_start);

  pool_masked_all_kernel<<<dim3(BATCH, 12), 256, 0, stream>>>(
      A2tok, A2desc, logits_tok, logits_desc, tok_pool, da_pool, dn_pool);
  pool_tiled_seg_kernel<<<dim3(BATCH, 4), 256, 0, stream>>>(
      A2node, logits_node, seg_start, ast_pool);

  code_gemm_kernel<<<dim3(4, 16), 256, 0, stream>>>(tok_pool, ast_pool, Wf, parts);
  sims_kernel<<<BATCH, 256, 0, stream>>>(parts, bfv, da_pool, dn_pool, terms);
  loss_kernel<<<1, 128, 0, stream>>>(terms, (float*)d_out);
}